// Round 2
// baseline (522.608 us; speedup 1.0000x reference)
//
#include <hip/hip_runtime.h>
#include <hip/hip_bf16.h>
#include <cstdint>

#define N_HID 384
#define BM 128
#define BN 128
#define BK 64
#define KTILES 6   // N_HID / BK

typedef __attribute__((ext_vector_type(8))) short bf16x8;
typedef __attribute__((ext_vector_type(4))) float f32x4;

static __device__ __forceinline__ short f2bf(float f) {
    union { __hip_bfloat16 h; short s; } u;
    u.h = __float2bfloat16(f);  // RNE
    return u.s;
}

// async global->LDS, 16B per lane; LDS dest = wave-uniform base + lane*16
static __device__ __forceinline__ void gload_lds16(const void* g, void* l) {
    __builtin_amdgcn_global_load_lds(
        (const __attribute__((address_space(1))) void*)g,
        (__attribute__((address_space(3))) void*)l,
        16, 0, 0);
}

// merged edge histograms: deg over row (for norm), cnt over col (for CSR)
__global__ __launch_bounds__(256) void k_hist(const int* __restrict__ row,
                                              const int* __restrict__ col,
                                              int* __restrict__ deg,
                                              int* __restrict__ cnt, int E) {
    int i = blockIdx.x * 256 + threadIdx.x;
    if (i < E) {
        atomicAdd(&deg[row[i]], 1);
        atomicAdd(&cnt[col[i]], 1);
    }
}

// ---------- CSR-by-destination build ----------

__global__ __launch_bounds__(256) void k_scan1(const int* __restrict__ cnt,
                                               int* __restrict__ offs,
                                               int* __restrict__ bsum, int N) {
    __shared__ int s[256];
    const int t = threadIdx.x;
    const int base = blockIdx.x * 1024 + t * 4;
    int v[4], tot = 0;
    #pragma unroll
    for (int i = 0; i < 4; i++) { v[i] = (base + i < N) ? cnt[base + i] : 0; tot += v[i]; }
    s[t] = tot;
    __syncthreads();
    #pragma unroll
    for (int off = 1; off < 256; off <<= 1) {
        int x = (t >= off) ? s[t - off] : 0;
        __syncthreads();
        s[t] += x;
        __syncthreads();
    }
    if (t == 255) bsum[blockIdx.x] = s[255];
    int run = s[t] - tot;
    #pragma unroll
    for (int i = 0; i < 4; i++) { if (base + i < N) offs[base + i] = run; run += v[i]; }
}

__global__ __launch_bounds__(256) void k_scan2(int* __restrict__ bsum, int nb) {
    __shared__ int s[256];
    const int t = threadIdx.x;
    int v = (t < nb) ? bsum[t] : 0;
    s[t] = v;
    __syncthreads();
    #pragma unroll
    for (int off = 1; off < 256; off <<= 1) {
        int x = (t >= off) ? s[t - off] : 0;
        __syncthreads();
        s[t] += x;
        __syncthreads();
    }
    if (t < nb) bsum[t] = s[t] - v;   // exclusive
}

__global__ __launch_bounds__(256) void k_scan3(int* __restrict__ offs,
                                               const int* __restrict__ bsum, int N) {
    int i = blockIdx.x * 256 + threadIdx.x;
    if (i < N) offs[i] += bsum[i >> 10];
}

// slot fill: packed (src, norm) per CSR slot; norm computed from deg directly
__global__ __launch_bounds__(256) void k_fill(const int* __restrict__ row,
                                              const int* __restrict__ col,
                                              const int* __restrict__ deg,
                                              const int* __restrict__ offs,
                                              int* __restrict__ cur,
                                              int2* __restrict__ srcnrm, int E) {
    int e = blockIdx.x * 256 + threadIdx.x;
    if (e >= E) return;
    int r = row[e], c = col[e];
    int slot = offs[c] + atomicAdd(&cur[c], 1);
    int2 p;
    p.x = r;
    p.y = __float_as_int(rsqrtf((float)deg[r]) * rsqrtf((float)deg[c]));
    srcnrm[slot] = p;
}

// ---------- W-prep: w1t = W1^T (bf16), w2b = W2 (bf16), wb1 = W2 @ b1 (fp32)
__global__ __launch_bounds__(256) void k_prep(const float* __restrict__ W1,
                                              const float* __restrict__ W2,
                                              const float* __restrict__ b1,
                                              short* __restrict__ w1t,
                                              short* __restrict__ w2b,
                                              float* __restrict__ wb1) {
    const int bid = blockIdx.x, t = threadIdx.x;
    if (bid < 144) {            // transpose W1 -> bf16, 12x12 tiles of 32x32
        __shared__ short tl[32][33];
        const int tx = bid % 12, ty = bid / 12;
        const int c = t & 31, r8 = t >> 5;      // 32 cols x 8 rows per pass
        #pragma unroll
        for (int rr = 0; rr < 32; rr += 8)
            tl[c][rr + r8] = f2bf(W1[(ty * 32 + rr + r8) * N_HID + tx * 32 + c]);
        __syncthreads();
        #pragma unroll
        for (int rr = 0; rr < 32; rr += 8)
            w1t[(tx * 32 + rr + r8) * N_HID + ty * 32 + c] = tl[rr + r8][c];
    } else if (bid < 288) {     // cvt W2 -> bf16 (float4/short4 per thread)
        int i = (bid - 144) * 256 + t;          // 36864 float4 groups total
        float4 v = reinterpret_cast<const float4*>(W2)[i];
        reinterpret_cast<short4*>(w2b)[i] =
            make_short4(f2bf(v.x), f2bf(v.y), f2bf(v.z), f2bf(v.w));
    } else {                    // wb1[n] = sum_k W2[n][k]*b1[k]; 2 blocks x 192
        int n = (bid - 288) * 192 + t;
        if (t < 192) {
            float s = 0.f;
            for (int k = 0; k < N_HID; k += 4) {
                float4 w = *reinterpret_cast<const float4*>(&W2[n * N_HID + k]);
                float4 b = *reinterpret_cast<const float4*>(&b1[k]);
                s += w.x * b.x + w.y * b.y + w.z * b.z + w.w * b.w;
            }
            wb1[n] = s;
        }
    }
}

// ---------- GEMM: acc[m][n] = sum_k A[m][k]*W[n][k]  (A,W bf16) ----------
// A staged via async global->LDS (double-buffered, 32 KiB). W (the B operand)
// is tiny (384x384 bf16 = 295 KB, L2-resident) -> read fragments DIRECTLY
// from global, no LDS staging. Halved LDS -> 4 blocks/CU (launch_bounds 256,4)
// vs 2 before: latency-bound GEMM gets 2x resident waves.
// FUSED=false: out bf16 = acc + bias[n]                (tiny W12 = W2*W1)
// FUSED=true : out fp32 = acc + dd[m]*wb1[n] + d[m]*bias[n]   (final output)
template <bool FUSED>
__global__ __launch_bounds__(256, 4) void k_gemm(const short* __restrict__ A,
                                                 const short* __restrict__ W,
                                                 const float* __restrict__ bias,
                                                 const float* __restrict__ wb1,
                                                 const float* __restrict__ dvec,
                                                 const float* __restrict__ ddvec,
                                                 void* __restrict__ outv,
                                                 int M, int MT) {
    __shared__ short As[2][BM][BK];   // 32 KiB total
    const int t = threadIdx.x;
    const int bid = blockIdx.x;
    // XCD-aware: XCD c=bid%8 gets 3 consecutive blocks sharing one m-tile
    const int m_idx = ((bid >> 3) / 3) * 8 + (bid & 7);
    const int n_idx = (bid >> 3) % 3;
    if (m_idx >= MT) return;
    const int m0 = m_idx * BM, n0 = n_idx * BN;
    const int wave = t >> 6, lane = t & 63;
    const int wm = (wave & 1) * 64, wn = (wave >> 1) * 64;
    const int l16 = lane & 15, quad = lane >> 4;
    const int srow = lane >> 3;
    const int sg8 = ((lane & 7) ^ srow) * 8;   // XOR chunk swizzle
    const int sbase = wave * 8;

    f32x4 acc[4][4] = {};

    // per-j B row base (j unrolled everywhere -> static indexing, stays in regs)
    const short* wb[4];
    #pragma unroll
    for (int j = 0; j < 4; j++)
        wb[j] = W + (size_t)(n0 + wn + j * 16 + l16) * N_HID;

    auto stage = [&](int b, int kt) {
        #pragma unroll
        for (int p = 0; p < 4; p++) {
            int gm = m0 + p * 32 + sbase + srow;
            gm = gm < M ? gm : M - 1;
            gload_lds16(A + (size_t)gm * N_HID + kt + sg8, &As[b][p * 32 + sbase][0]);
        }
    };

    stage(0, 0);
    #pragma unroll
    for (int kt6 = 0; kt6 < KTILES; kt6++) {
        const int b = kt6 & 1;
        __syncthreads();
        if (kt6 + 1 < KTILES) stage(1 - b, (kt6 + 1) * BK);
        #pragma unroll
        for (int kk = 0; kk < 2; kk++) {
            const int gc = kk * 4 + quad;
            bf16x8 af[4];
            #pragma unroll
            for (int i = 0; i < 4; i++)
                af[i] = *reinterpret_cast<const bf16x8*>(&As[b][wm + i * 16 + l16][(gc ^ (l16 & 7)) * 8]);
            #pragma unroll
            for (int j = 0; j < 4; j++) {
                bf16x8 bfr = *reinterpret_cast<const bf16x8*>(wb[j] + kt6 * BK + gc * 8);
                #pragma unroll
                for (int i = 0; i < 4; i++)
                    acc[i][j] = __builtin_amdgcn_mfma_f32_16x16x32_bf16(af[i], bfr, acc[i][j], 0, 0, 0);
            }
        }
    }

    // C/D layout: col = lane&15, row = quad*4 + reg
    if (FUSED) {
        // fp32 direct stores: 16 lanes x 4B = full 64B lines, no RMW
        float* outf = (float*)outv;
        float dv[4][4], ddv[4][4];
        #pragma unroll
        for (int i = 0; i < 4; i++)
            #pragma unroll
            for (int r = 0; r < 4; r++) {
                int gm = m0 + wm + i * 16 + quad * 4 + r;
                int gmc = gm < M ? gm : 0;
                dv[i][r]  = dvec[gmc];
                ddv[i][r] = ddvec[gmc];
            }
        #pragma unroll
        for (int j = 0; j < 4; j++) {
            int gn = n0 + wn + j * 16 + l16;
            float wb1v = wb1[gn];
            float b2v  = bias[gn];
            #pragma unroll
            for (int i = 0; i < 4; i++) {
                int gmb = m0 + wm + i * 16 + quad * 4;
                #pragma unroll
                for (int r = 0; r < 4; r++) {
                    int gm = gmb + r;
                    if (gm < M)
                        outf[(size_t)gm * N_HID + gn] =
                            acc[i][j][r] + ddv[i][r] * wb1v + dv[i][r] * b2v;
                }
            }
        }
    } else {
        // bf16 out via LDS repack -> 16B coalesced stores
        short* outb = (short*)outv;
        __syncthreads();
        short* eps = &As[0][0][0] + wave * 4096;
        #pragma unroll
        for (int j = 0; j < 4; j++) {
            float bv = bias[n0 + wn + j * 16 + l16];
            #pragma unroll
            for (int i = 0; i < 4; i++)
                #pragma unroll
                for (int r = 0; r < 4; r++) {
                    int rw = i * 16 + quad * 4 + r;
                    int colw = j * 16 + l16;
                    int chs = ((colw >> 3) + (rw & 7) + (rw >> 3)) & 7;
                    eps[rw * 64 + chs * 8 + (colw & 7)] = f2bf(acc[i][j][r] + bv);
                }
        }
        __syncthreads();
        const int r8 = lane >> 3, ch2 = lane & 7;
        #pragma unroll
        for (int pass = 0; pass < 8; pass++) {
            int rw = pass * 8 + r8;
            int chs = (ch2 + r8 + pass) & 7;
            bf16x8 v = *reinterpret_cast<const bf16x8*>(&eps[rw * 64 + chs * 8]);
            int gm = m0 + wm + rw;
            if (gm < M)
                *reinterpret_cast<bf16x8*>(outb + (size_t)gm * N_HID + n0 + wn + ch2 * 8) = v;
        }
    }
}

// ---------- gather: one wave per destination node, edge loop unrolled x2 ----
// SECOND=false: in = x (fp32), ds = sum(w)           -> d
// SECOND=true : in = g1 (bf16), ds = sum(w*din[src]) -> dd
template <bool SECOND>
__global__ __launch_bounds__(256) void k_gather(const void* __restrict__ inv,
                                                const int2* __restrict__ srcnrm,
                                                const int* __restrict__ offs,
                                                const int* __restrict__ cur,
                                                const float* __restrict__ din,
                                                unsigned int* __restrict__ outg,
                                                float* __restrict__ dout, int N) {
    int node = (blockIdx.x * 256 + threadIdx.x) >> 6;
    if (node >= N) return;
    int lane = threadIdx.x & 63;
    int start = offs[node];
    int ecnt  = cur[node];   // in-degree
    float2 acc[3] = {};
    float ds = 0.f;
    int i = 0;
    for (; i + 2 <= ecnt; i += 2) {          // pairs: independent load streams
        int2 pa = srcnrm[start + i];
        int2 pb = srcnrm[start + i + 1];
        float wa = __int_as_float(pa.y), wb = __int_as_float(pb.y);
        float2 va[3], vb[3];
        if (SECOND) {
            const unsigned int* ra = (const unsigned int*)inv + (size_t)pa.x * 192;
            const unsigned int* rb = (const unsigned int*)inv + (size_t)pb.x * 192;
            unsigned int ua[3], ub[3];
            #pragma unroll
            for (int k = 0; k < 3; k++) { ua[k] = ra[lane + 64 * k]; ub[k] = rb[lane + 64 * k]; }
            #pragma unroll
            for (int k = 0; k < 3; k++) {
                va[k].x = __uint_as_float(ua[k] << 16);
                va[k].y = __uint_as_float(ua[k] & 0xffff0000u);
                vb[k].x = __uint_as_float(ub[k] << 16);
                vb[k].y = __uint_as_float(ub[k] & 0xffff0000u);
            }
            ds += wa * din[pa.x] + wb * din[pb.x];
        } else {
            const float2* ra = (const float2*)inv + (size_t)pa.x * 192;
            const float2* rb = (const float2*)inv + (size_t)pb.x * 192;
            #pragma unroll
            for (int k = 0; k < 3; k++) { va[k] = ra[lane + 64 * k]; vb[k] = rb[lane + 64 * k]; }
            ds += wa + wb;
        }
        #pragma unroll
        for (int k = 0; k < 3; k++) {
            acc[k].x += wa * va[k].x; acc[k].y += wa * va[k].y;
            acc[k].x += wb * vb[k].x; acc[k].y += wb * vb[k].y;
        }
    }
    if (i < ecnt) {                          // tail edge
        int2 p = srcnrm[start + i];
        float w = __int_as_float(p.y);
        if (SECOND) {
            const unsigned int* r = (const unsigned int*)inv + (size_t)p.x * 192;
            #pragma unroll
            for (int k = 0; k < 3; k++) {
                unsigned int u = r[lane + 64 * k];
                acc[k].x += w * __uint_as_float(u << 16);
                acc[k].y += w * __uint_as_float(u & 0xffff0000u);
            }
            ds += w * din[p.x];
        } else {
            const float2* r = (const float2*)inv + (size_t)p.x * 192;
            #pragma unroll
            for (int k = 0; k < 3; k++) {
                float2 v = r[lane + 64 * k];
                acc[k].x += w * v.x; acc[k].y += w * v.y;
            }
            ds += w;
        }
    }
    #pragma unroll
    for (int k = 0; k < 3; k++) {
        unsigned int lo = (unsigned int)(unsigned short)f2bf(acc[k].x);
        unsigned int hi = (unsigned int)(unsigned short)f2bf(acc[k].y);
        outg[(size_t)node * 192 + lane + 64 * k] = lo | (hi << 16);
    }
    if (lane == 0) dout[node] = ds;
}

extern "C" void kernel_launch(void* const* d_in, const int* in_sizes, int n_in,
                              void* d_out, int out_size, void* d_ws, size_t ws_size,
                              hipStream_t stream) {
    const float* x  = (const float*)d_in[0];
    const int*   ei = (const int*)d_in[1];
    const float* W1 = (const float*)d_in[2];
    const float* b1 = (const float*)d_in[3];
    const float* W2 = (const float*)d_in[4];
    const float* b2 = (const float*)d_in[5];

    const int N = in_sizes[0] / N_HID;   // 100000
    const int E = in_sizes[1] / 2;       // 200000
    const int* row = ei;
    const int* col = ei + E;
    const int nb = (N + 1023) / 1024;    // 98 (<=256 for k_scan2)

    // g1 (bf16, 76.8 MB) lives in d_out's first half; dead before the final
    // GEMM rewrites all of d_out in fp32.
    unsigned int* g1 = (unsigned int*)d_out;

    auto al = [](size_t v) { return (v + 255) & ~(size_t)255; };
    char* ws = (char*)d_ws;
    size_t o = 0;
    int*   deg    = (int*)(ws + o);   o += al((size_t)N * 4);
    int*   offs   = (int*)(ws + o);   o += al((size_t)N * 4);   // cnt -> offs in place
    float* zeros  = (float*)(ws + o); o += al(N_HID * 4);       // tiny-GEMM bias
    int*   cur    = (int*)(ws + o);   o += al((size_t)N * 4);
    // --- everything above zeroed by ONE memset ---
    const size_t zlen = o;
    int*   bsum   = (int*)(ws + o);   o += al((size_t)nb * 4);
    int2*  srcnrm = (int2*)(ws + o);  o += al((size_t)E * 8);
    short* w1t    = (short*)(ws + o); o += al((size_t)N_HID * N_HID * 2);
    short* w2b    = (short*)(ws + o); o += al((size_t)N_HID * N_HID * 2);
    short* w12    = (short*)(ws + o); o += al((size_t)N_HID * N_HID * 2);
    float* wb1    = (float*)(ws + o); o += al(N_HID * 4);
    float* dvec   = (float*)(ws + o); o += al((size_t)N * 4);
    float* ddvec  = (float*)(ws + o); o += al((size_t)N * 4);
    unsigned int* g2 = (unsigned int*)(ws + o);                  // N*384 bf16

    hipMemsetAsync(deg, 0, zlen, stream);

    // CSR build: deg/cnt histograms -> scan -> slot fill (norm from deg)
    k_hist<<<(E + 255) / 256, 256, 0, stream>>>(row, col, deg, offs, E);
    k_scan1<<<nb, 256, 0, stream>>>(offs, offs, bsum, N);
    k_scan2<<<1, 256, 0, stream>>>(bsum, nb);
    k_scan3<<<(N + 255) / 256, 256, 0, stream>>>(offs, bsum, N);
    k_fill<<<(E + 255) / 256, 256, 0, stream>>>(row, col, deg, offs, cur, srcnrm, E);

    // W-prep + tiny GEMM: w12 = W2 @ W1 (bf16), wb1 = W2 @ b1
    k_prep<<<290, 256, 0, stream>>>(W1, W2, b1, w1t, w2b, wb1);
    k_gemm<false><<<24, 256, 0, stream>>>(w2b, w1t, zeros, nullptr, nullptr, nullptr,
                                          w12, N_HID, 3);

    // g1 = A_hat @ x (fp32 in, bf16 out), d = A_hat @ 1
    // g2 = A_hat @ g1,                    dd = A_hat @ d
    const int gat_blocks = (int)(((size_t)N * 64 + 255) / 256);
    k_gather<false><<<gat_blocks, 256, 0, stream>>>(x,  srcnrm, offs, cur, nullptr, g1, dvec, N);
    k_gather<true><<<gat_blocks, 256, 0, stream>>>(g1, srcnrm, offs, cur, dvec, g2, ddvec, N);

    // out = g2 @ w12^T + dd*wb1^T + d*b2^T   (fp32, fully rewrites d_out)
    const int MT = (N + BM - 1) / BM;            // 782
    const int gblocks = ((MT + 7) / 8) * 24;     // 2352
    k_gemm<true><<<gblocks, 256, 0, stream>>>((const short*)g2, w12, b2, wb1, dvec, ddvec,
                                              d_out, N, MT);
}

// Round 3
// 494.548 us; speedup vs baseline: 1.0567x; 1.0567x over previous
//
#include <hip/hip_runtime.h>
#include <hip/hip_bf16.h>
#include <cstdint>

#define N_HID 384
#define BM 128
#define BN 128
#define BK 64
#define KTILES 6   // N_HID / BK

typedef __attribute__((ext_vector_type(8))) short bf16x8;
typedef __attribute__((ext_vector_type(4))) float f32x4;

static __device__ __forceinline__ short f2bf(float f) {
    union { __hip_bfloat16 h; short s; } u;
    u.h = __float2bfloat16(f);  // RNE
    return u.s;
}

// async global->LDS, 16B per lane; LDS dest = wave-uniform base + lane*16
static __device__ __forceinline__ void gload_lds16(const void* g, void* l) {
    __builtin_amdgcn_global_load_lds(
        (const __attribute__((address_space(1))) void*)g,
        (__attribute__((address_space(3))) void*)l,
        16, 0, 0);
}

// merged edge histograms: deg over row (for norm), cnt over col (for CSR)
__global__ __launch_bounds__(256) void k_hist(const int* __restrict__ row,
                                              const int* __restrict__ col,
                                              int* __restrict__ deg,
                                              int* __restrict__ cnt, int E) {
    int i = blockIdx.x * 256 + threadIdx.x;
    if (i < E) {
        atomicAdd(&deg[row[i]], 1);
        atomicAdd(&cnt[col[i]], 1);
    }
}

// ---------- CSR-by-destination build ----------

__global__ __launch_bounds__(256) void k_scan1(const int* __restrict__ cnt,
                                               int* __restrict__ offs,
                                               int* __restrict__ bsum, int N) {
    __shared__ int s[256];
    const int t = threadIdx.x;
    const int base = blockIdx.x * 1024 + t * 4;
    int v[4], tot = 0;
    #pragma unroll
    for (int i = 0; i < 4; i++) { v[i] = (base + i < N) ? cnt[base + i] : 0; tot += v[i]; }
    s[t] = tot;
    __syncthreads();
    #pragma unroll
    for (int off = 1; off < 256; off <<= 1) {
        int x = (t >= off) ? s[t - off] : 0;
        __syncthreads();
        s[t] += x;
        __syncthreads();
    }
    if (t == 255) bsum[blockIdx.x] = s[255];
    int run = s[t] - tot;
    #pragma unroll
    for (int i = 0; i < 4; i++) { if (base + i < N) offs[base + i] = run; run += v[i]; }
}

__global__ __launch_bounds__(256) void k_scan2(int* __restrict__ bsum, int nb) {
    __shared__ int s[256];
    const int t = threadIdx.x;
    int v = (t < nb) ? bsum[t] : 0;
    s[t] = v;
    __syncthreads();
    #pragma unroll
    for (int off = 1; off < 256; off <<= 1) {
        int x = (t >= off) ? s[t - off] : 0;
        __syncthreads();
        s[t] += x;
        __syncthreads();
    }
    if (t < nb) bsum[t] = s[t] - v;   // exclusive
}

__global__ __launch_bounds__(256) void k_scan3(int* __restrict__ offs,
                                               const int* __restrict__ bsum, int N) {
    int i = blockIdx.x * 256 + threadIdx.x;
    if (i < N) offs[i] += bsum[i >> 10];
}

// slot fill: packed (src, norm) per CSR slot; norm computed from deg directly
__global__ __launch_bounds__(256) void k_fill(const int* __restrict__ row,
                                              const int* __restrict__ col,
                                              const int* __restrict__ deg,
                                              const int* __restrict__ offs,
                                              int* __restrict__ cur,
                                              int2* __restrict__ srcnrm, int E) {
    int e = blockIdx.x * 256 + threadIdx.x;
    if (e >= E) return;
    int r = row[e], c = col[e];
    int slot = offs[c] + atomicAdd(&cur[c], 1);
    int2 p;
    p.x = r;
    p.y = __float_as_int(rsqrtf((float)deg[r]) * rsqrtf((float)deg[c]));
    srcnrm[slot] = p;
}

// ---------- W-prep: w1t = W1^T (bf16), w2b = W2 (bf16), wb1 = W2 @ b1 (fp32)
__global__ __launch_bounds__(256) void k_prep(const float* __restrict__ W1,
                                              const float* __restrict__ W2,
                                              const float* __restrict__ b1,
                                              short* __restrict__ w1t,
                                              short* __restrict__ w2b,
                                              float* __restrict__ wb1) {
    const int bid = blockIdx.x, t = threadIdx.x;
    if (bid < 144) {            // transpose W1 -> bf16, 12x12 tiles of 32x32
        __shared__ short tl[32][33];
        const int tx = bid % 12, ty = bid / 12;
        const int c = t & 31, r8 = t >> 5;      // 32 cols x 8 rows per pass
        #pragma unroll
        for (int rr = 0; rr < 32; rr += 8)
            tl[c][rr + r8] = f2bf(W1[(ty * 32 + rr + r8) * N_HID + tx * 32 + c]);
        __syncthreads();
        #pragma unroll
        for (int rr = 0; rr < 32; rr += 8)
            w1t[(tx * 32 + rr + r8) * N_HID + ty * 32 + c] = tl[rr + r8][c];
    } else if (bid < 288) {     // cvt W2 -> bf16 (float4/short4 per thread)
        int i = (bid - 144) * 256 + t;          // 36864 float4 groups total
        float4 v = reinterpret_cast<const float4*>(W2)[i];
        reinterpret_cast<short4*>(w2b)[i] =
            make_short4(f2bf(v.x), f2bf(v.y), f2bf(v.z), f2bf(v.w));
    } else {                    // wb1[n] = sum_k W2[n][k]*b1[k]; 2 blocks x 192
        int n = (bid - 288) * 192 + t;
        if (t < 192) {
            float s = 0.f;
            for (int k = 0; k < N_HID; k += 4) {
                float4 w = *reinterpret_cast<const float4*>(&W2[n * N_HID + k]);
                float4 b = *reinterpret_cast<const float4*>(&b1[k]);
                s += w.x * b.x + w.y * b.y + w.z * b.z + w.w * b.w;
            }
            wb1[n] = s;
        }
    }
}

// ---------- GEMM: acc[m][n] = sum_k A[m][k]*W[n][k]  (A,W bf16) ----------
// A staged via async global->LDS (double-buffered, 32 KiB, round-0 swizzle).
// W (B operand, 384x384 bf16 = 295 KB, L2-resident): fragments loaded
// global->REGISTER one full K-step ahead (bfr[2][8], statically indexed under
// the fully unrolled K loop) -- same in-flight window as the LDS path gave,
// but no LDS round-trip and the per-step barrier drain waits on 4 A-gloads
// instead of 8 A+B. Plain launch_bounds: do NOT squeeze VGPRs (round-2
// lesson: forcing 64 arch VGPRs cripples scheduling).
// FUSED=false: out bf16 = acc + bias[n]                (tiny W12 = W2*W1)
// FUSED=true : out fp32 = acc + dd[m]*wb1[n] + d[m]*bias[n]   (final output)
template <bool FUSED>
__global__ __launch_bounds__(256) void k_gemm(const short* __restrict__ A,
                                              const short* __restrict__ W,
                                              const float* __restrict__ bias,
                                              const float* __restrict__ wb1,
                                              const float* __restrict__ dvec,
                                              const float* __restrict__ ddvec,
                                              void* __restrict__ outv,
                                              int M, int MT) {
    __shared__ short As[2][BM][BK];   // 32 KiB
    const int t = threadIdx.x;
    const int bid = blockIdx.x;
    // XCD-aware: XCD c=bid%8 gets 3 consecutive blocks sharing one m-tile
    const int m_idx = ((bid >> 3) / 3) * 8 + (bid & 7);
    const int n_idx = (bid >> 3) % 3;
    if (m_idx >= MT) return;
    const int m0 = m_idx * BM, n0 = n_idx * BN;
    const int wave = t >> 6, lane = t & 63;
    const int wm = (wave & 1) * 64, wn = (wave >> 1) * 64;
    const int l16 = lane & 15, quad = lane >> 4;
    const int srow = lane >> 3;
    const int sg8 = ((lane & 7) ^ srow) * 8;   // XOR chunk swizzle
    const int sbase = wave * 8;

    f32x4 acc[4][4] = {};

    // per-j B row base (statically unrolled -> stays in SGPR/VGPR, no scratch)
    const short* wrow[4];
    #pragma unroll
    for (int j = 0; j < 4; j++)
        wrow[j] = W + (size_t)(n0 + wn + j * 16 + l16) * N_HID;

    auto stageA = [&](int b, int kt) {
        #pragma unroll
        for (int p = 0; p < 4; p++) {
            int gm = m0 + p * 32 + sbase + srow;
            gm = gm < M ? gm : M - 1;
            gload_lds16(A + (size_t)gm * N_HID + kt + sg8, &As[b][p * 32 + sbase][0]);
        }
    };

    // load the 8 B fragments (2 kk-halves x 4 j) for K-step kt into regs
    auto ldB = [&](bf16x8* dst, int kt) {
        #pragma unroll
        for (int kk = 0; kk < 2; kk++) {
            const int gc = kk * 4 + quad;
            #pragma unroll
            for (int j = 0; j < 4; j++)
                dst[kk * 4 + j] = *reinterpret_cast<const bf16x8*>(wrow[j] + kt + gc * 8);
        }
    };

    bf16x8 bfr[2][8];
    stageA(0, 0);
    ldB(bfr[0], 0);
    #pragma unroll
    for (int kt6 = 0; kt6 < KTILES; kt6++) {
        const int b = kt6 & 1;
        __syncthreads();
        if (kt6 + 1 < KTILES) {
            stageA(1 - b, (kt6 + 1) * BK);
            ldB(bfr[(kt6 + 1) & 1], (kt6 + 1) * BK);
        }
        #pragma unroll
        for (int kk = 0; kk < 2; kk++) {
            const int gc = kk * 4 + quad;
            bf16x8 af[4];
            #pragma unroll
            for (int i = 0; i < 4; i++)
                af[i] = *reinterpret_cast<const bf16x8*>(&As[b][wm + i * 16 + l16][(gc ^ (l16 & 7)) * 8]);
            #pragma unroll
            for (int j = 0; j < 4; j++)
                #pragma unroll
                for (int i = 0; i < 4; i++)
                    acc[i][j] = __builtin_amdgcn_mfma_f32_16x16x32_bf16(af[i], bfr[kt6 & 1][kk * 4 + j], acc[i][j], 0, 0, 0);
        }
    }

    // C/D layout: col = lane&15, row = quad*4 + reg
    if (FUSED) {
        // fp32 direct stores: 16 lanes x 4B = full 64B lines, no RMW
        float* outf = (float*)outv;
        float dv[4][4], ddv[4][4];
        #pragma unroll
        for (int i = 0; i < 4; i++)
            #pragma unroll
            for (int r = 0; r < 4; r++) {
                int gm = m0 + wm + i * 16 + quad * 4 + r;
                int gmc = gm < M ? gm : 0;
                dv[i][r]  = dvec[gmc];
                ddv[i][r] = ddvec[gmc];
            }
        #pragma unroll
        for (int j = 0; j < 4; j++) {
            int gn = n0 + wn + j * 16 + l16;
            float wb1v = wb1[gn];
            float b2v  = bias[gn];
            #pragma unroll
            for (int i = 0; i < 4; i++) {
                int gmb = m0 + wm + i * 16 + quad * 4;
                #pragma unroll
                for (int r = 0; r < 4; r++) {
                    int gm = gmb + r;
                    if (gm < M)
                        outf[(size_t)gm * N_HID + gn] =
                            acc[i][j][r] + ddv[i][r] * wb1v + dv[i][r] * b2v;
                }
            }
        }
    } else {
        // bf16 out via LDS repack -> 16B coalesced stores
        short* outb = (short*)outv;
        __syncthreads();
        short* eps = &As[0][0][0] + wave * 4096;   // 4 waves x 8 KB = all 32 KiB
        #pragma unroll
        for (int j = 0; j < 4; j++) {
            float bv = bias[n0 + wn + j * 16 + l16];
            #pragma unroll
            for (int i = 0; i < 4; i++)
                #pragma unroll
                for (int r = 0; r < 4; r++) {
                    int rw = i * 16 + quad * 4 + r;
                    int colw = j * 16 + l16;
                    int chs = ((colw >> 3) + (rw & 7) + (rw >> 3)) & 7;
                    eps[rw * 64 + chs * 8 + (colw & 7)] = f2bf(acc[i][j][r] + bv);
                }
        }
        __syncthreads();
        const int r8 = lane >> 3, ch2 = lane & 7;
        #pragma unroll
        for (int pass = 0; pass < 8; pass++) {
            int rw = pass * 8 + r8;
            int chs = (ch2 + r8 + pass) & 7;
            bf16x8 v = *reinterpret_cast<const bf16x8*>(&eps[rw * 64 + chs * 8]);
            int gm = m0 + wm + rw;
            if (gm < M)
                *reinterpret_cast<bf16x8*>(outb + (size_t)gm * N_HID + n0 + wn + ch2 * 8) = v;
        }
    }
}

// ---------- gather: one wave per destination node, edge loop unrolled x2 ----
// SECOND=false: in = x (fp32), ds = sum(w)           -> d
// SECOND=true : in = g1 (bf16), ds = sum(w*din[src]) -> dd
template <bool SECOND>
__global__ __launch_bounds__(256) void k_gather(const void* __restrict__ inv,
                                                const int2* __restrict__ srcnrm,
                                                const int* __restrict__ offs,
                                                const int* __restrict__ cur,
                                                const float* __restrict__ din,
                                                unsigned int* __restrict__ outg,
                                                float* __restrict__ dout, int N) {
    int node = (blockIdx.x * 256 + threadIdx.x) >> 6;
    if (node >= N) return;
    int lane = threadIdx.x & 63;
    int start = offs[node];
    int ecnt  = cur[node];   // in-degree
    float2 acc[3] = {};
    float ds = 0.f;
    int i = 0;
    for (; i + 2 <= ecnt; i += 2) {          // pairs: independent load streams
        int2 pa = srcnrm[start + i];
        int2 pb = srcnrm[start + i + 1];
        float wa = __int_as_float(pa.y), wb = __int_as_float(pb.y);
        float2 va[3], vb[3];
        if (SECOND) {
            const unsigned int* ra = (const unsigned int*)inv + (size_t)pa.x * 192;
            const unsigned int* rb = (const unsigned int*)inv + (size_t)pb.x * 192;
            unsigned int ua[3], ub[3];
            #pragma unroll
            for (int k = 0; k < 3; k++) { ua[k] = ra[lane + 64 * k]; ub[k] = rb[lane + 64 * k]; }
            #pragma unroll
            for (int k = 0; k < 3; k++) {
                va[k].x = __uint_as_float(ua[k] << 16);
                va[k].y = __uint_as_float(ua[k] & 0xffff0000u);
                vb[k].x = __uint_as_float(ub[k] << 16);
                vb[k].y = __uint_as_float(ub[k] & 0xffff0000u);
            }
            ds += wa * din[pa.x] + wb * din[pb.x];
        } else {
            const float2* ra = (const float2*)inv + (size_t)pa.x * 192;
            const float2* rb = (const float2*)inv + (size_t)pb.x * 192;
            #pragma unroll
            for (int k = 0; k < 3; k++) { va[k] = ra[lane + 64 * k]; vb[k] = rb[lane + 64 * k]; }
            ds += wa + wb;
        }
        #pragma unroll
        for (int k = 0; k < 3; k++) {
            acc[k].x += wa * va[k].x; acc[k].y += wa * va[k].y;
            acc[k].x += wb * vb[k].x; acc[k].y += wb * vb[k].y;
        }
    }
    if (i < ecnt) {                          // tail edge
        int2 p = srcnrm[start + i];
        float w = __int_as_float(p.y);
        if (SECOND) {
            const unsigned int* r = (const unsigned int*)inv + (size_t)p.x * 192;
            #pragma unroll
            for (int k = 0; k < 3; k++) {
                unsigned int u = r[lane + 64 * k];
                acc[k].x += w * __uint_as_float(u << 16);
                acc[k].y += w * __uint_as_float(u & 0xffff0000u);
            }
            ds += w * din[p.x];
        } else {
            const float2* r = (const float2*)inv + (size_t)p.x * 192;
            #pragma unroll
            for (int k = 0; k < 3; k++) {
                float2 v = r[lane + 64 * k];
                acc[k].x += w * v.x; acc[k].y += w * v.y;
            }
            ds += w;
        }
    }
    #pragma unroll
    for (int k = 0; k < 3; k++) {
        unsigned int lo = (unsigned int)(unsigned short)f2bf(acc[k].x);
        unsigned int hi = (unsigned int)(unsigned short)f2bf(acc[k].y);
        outg[(size_t)node * 192 + lane + 64 * k] = lo | (hi << 16);
    }
    if (lane == 0) dout[node] = ds;
}

extern "C" void kernel_launch(void* const* d_in, const int* in_sizes, int n_in,
                              void* d_out, int out_size, void* d_ws, size_t ws_size,
                              hipStream_t stream) {
    const float* x  = (const float*)d_in[0];
    const int*   ei = (const int*)d_in[1];
    const float* W1 = (const float*)d_in[2];
    const float* b1 = (const float*)d_in[3];
    const float* W2 = (const float*)d_in[4];
    const float* b2 = (const float*)d_in[5];

    const int N = in_sizes[0] / N_HID;   // 100000
    const int E = in_sizes[1] / 2;       // 200000
    const int* row = ei;
    const int* col = ei + E;
    const int nb = (N + 1023) / 1024;    // 98 (<=256 for k_scan2)

    // g1 (bf16, 76.8 MB) lives in d_out's first half; dead before the final
    // GEMM rewrites all of d_out in fp32.
    unsigned int* g1 = (unsigned int*)d_out;

    auto al = [](size_t v) { return (v + 255) & ~(size_t)255; };
    char* ws = (char*)d_ws;
    size_t o = 0;
    int*   deg    = (int*)(ws + o);   o += al((size_t)N * 4);
    int*   offs   = (int*)(ws + o);   o += al((size_t)N * 4);   // cnt -> offs in place
    float* zeros  = (float*)(ws + o); o += al(N_HID * 4);       // tiny-GEMM bias
    int*   cur    = (int*)(ws + o);   o += al((size_t)N * 4);
    // --- everything above zeroed by ONE memset ---
    const size_t zlen = o;
    int*   bsum   = (int*)(ws + o);   o += al((size_t)nb * 4);
    int2*  srcnrm = (int2*)(ws + o);  o += al((size_t)E * 8);
    short* w1t    = (short*)(ws + o); o += al((size_t)N_HID * N_HID * 2);
    short* w2b    = (short*)(ws + o); o += al((size_t)N_HID * N_HID * 2);
    short* w12    = (short*)(ws + o); o += al((size_t)N_HID * N_HID * 2);
    float* wb1    = (float*)(ws + o); o += al(N_HID * 4);
    float* dvec   = (float*)(ws + o); o += al((size_t)N * 4);
    float* ddvec  = (float*)(ws + o); o += al((size_t)N * 4);
    unsigned int* g2 = (unsigned int*)(ws + o);                  // N*384 bf16

    hipMemsetAsync(deg, 0, zlen, stream);

    // CSR build: deg/cnt histograms -> scan -> slot fill (norm from deg)
    k_hist<<<(E + 255) / 256, 256, 0, stream>>>(row, col, deg, offs, E);
    k_scan1<<<nb, 256, 0, stream>>>(offs, offs, bsum, N);
    k_scan2<<<1, 256, 0, stream>>>(bsum, nb);
    k_scan3<<<(N + 255) / 256, 256, 0, stream>>>(offs, bsum, N);
    k_fill<<<(E + 255) / 256, 256, 0, stream>>>(row, col, deg, offs, cur, srcnrm, E);

    // W-prep + tiny GEMM: w12 = W2 @ W1 (bf16), wb1 = W2 @ b1
    k_prep<<<290, 256, 0, stream>>>(W1, W2, b1, w1t, w2b, wb1);
    k_gemm<false><<<24, 256, 0, stream>>>(w2b, w1t, zeros, nullptr, nullptr, nullptr,
                                          w12, N_HID, 3);

    // g1 = A_hat @ x (fp32 in, bf16 out), d = A_hat @ 1
    // g2 = A_hat @ g1,                    dd = A_hat @ d
    const int gat_blocks = (int)(((size_t)N * 64 + 255) / 256);
    k_gather<false><<<gat_blocks, 256, 0, stream>>>(x,  srcnrm, offs, cur, nullptr, g1, dvec, N);
    k_gather<true><<<gat_blocks, 256, 0, stream>>>(g1, srcnrm, offs, cur, dvec, g2, ddvec, N);

    // out = g2 @ w12^T + dd*wb1^T + d*b2^T   (fp32, fully rewrites d_out)
    const int MT = (N + BM - 1) / BM;            // 782
    const int gblocks = ((MT + 7) / 8) * 24;     // 2352
    k_gemm<true><<<gblocks, 256, 0, stream>>>((const short*)g2, w12, b2, wb1, dvec, ddvec,
                                              d_out, N, MT);
}

// Round 4
// 465.047 us; speedup vs baseline: 1.1238x; 1.0634x over previous
//
#include <hip/hip_runtime.h>
#include <hip/hip_bf16.h>
#include <cstdint>

#define N_HID 384
#define BM 128
#define BN 128
#define BK 64
#define KTILES 6   // N_HID / BK

typedef __attribute__((ext_vector_type(8))) short bf16x8;
typedef __attribute__((ext_vector_type(4))) float f32x4;

static __device__ __forceinline__ short f2bf(float f) {
    union { __hip_bfloat16 h; short s; } u;
    u.h = __float2bfloat16(f);  // RNE
    return u.s;
}

static __device__ __forceinline__ unsigned int pk2(float lo, float hi) {
    return (unsigned int)(unsigned short)f2bf(lo) |
           ((unsigned int)(unsigned short)f2bf(hi) << 16);
}

// async global->LDS, 16B per lane; LDS dest = wave-uniform base + lane*16
static __device__ __forceinline__ void gload_lds16(const void* g, void* l) {
    __builtin_amdgcn_global_load_lds(
        (const __attribute__((address_space(1))) void*)g,
        (__attribute__((address_space(3))) void*)l,
        16, 0, 0);
}

// merged edge histograms: deg over row (for norm), cnt over col (for CSR)
__global__ __launch_bounds__(256) void k_hist(const int* __restrict__ row,
                                              const int* __restrict__ col,
                                              int* __restrict__ deg,
                                              int* __restrict__ cnt, int E) {
    int i = blockIdx.x * 256 + threadIdx.x;
    if (i < E) {
        atomicAdd(&deg[row[i]], 1);
        atomicAdd(&cnt[col[i]], 1);
    }
}

// ---------- CSR-by-destination build ----------

__global__ __launch_bounds__(256) void k_scan1(const int* __restrict__ cnt,
                                               int* __restrict__ offs,
                                               int* __restrict__ bsum, int N) {
    __shared__ int s[256];
    const int t = threadIdx.x;
    const int base = blockIdx.x * 1024 + t * 4;
    int v[4], tot = 0;
    #pragma unroll
    for (int i = 0; i < 4; i++) { v[i] = (base + i < N) ? cnt[base + i] : 0; tot += v[i]; }
    s[t] = tot;
    __syncthreads();
    #pragma unroll
    for (int off = 1; off < 256; off <<= 1) {
        int x = (t >= off) ? s[t - off] : 0;
        __syncthreads();
        s[t] += x;
        __syncthreads();
    }
    if (t == 255) bsum[blockIdx.x] = s[255];
    int run = s[t] - tot;
    #pragma unroll
    for (int i = 0; i < 4; i++) { if (base + i < N) offs[base + i] = run; run += v[i]; }
}

__global__ __launch_bounds__(256) void k_scan2(int* __restrict__ bsum, int nb) {
    __shared__ int s[256];
    const int t = threadIdx.x;
    int v = (t < nb) ? bsum[t] : 0;
    s[t] = v;
    __syncthreads();
    #pragma unroll
    for (int off = 1; off < 256; off <<= 1) {
        int x = (t >= off) ? s[t - off] : 0;
        __syncthreads();
        s[t] += x;
        __syncthreads();
    }
    if (t < nb) bsum[t] = s[t] - v;   // exclusive
}

// slot fill: packed (src, norm) per CSR slot; norm computed from deg directly.
// bsum folded in here (k_scan3 eliminated): global offset = offs[c]+bsum[c>>10]
__global__ __launch_bounds__(256) void k_fill(const int* __restrict__ row,
                                              const int* __restrict__ col,
                                              const int* __restrict__ deg,
                                              const int* __restrict__ offs,
                                              const int* __restrict__ bsum,
                                              int* __restrict__ cur,
                                              int2* __restrict__ srcnrm, int E) {
    int e = blockIdx.x * 256 + threadIdx.x;
    if (e >= E) return;
    int r = row[e], c = col[e];
    int slot = offs[c] + bsum[c >> 10] + atomicAdd(&cur[c], 1);
    int2 p;
    p.x = r;
    p.y = __float_as_int(rsqrtf((float)deg[r]) * rsqrtf((float)deg[c]));
    srcnrm[slot] = p;
}

// ---------- W-prep: w1t = W1^T (bf16), w2b = W2 (bf16), wb1 = W2 @ b1 (fp32)
__global__ __launch_bounds__(256) void k_prep(const float* __restrict__ W1,
                                              const float* __restrict__ W2,
                                              const float* __restrict__ b1,
                                              short* __restrict__ w1t,
                                              short* __restrict__ w2b,
                                              float* __restrict__ wb1) {
    const int bid = blockIdx.x, t = threadIdx.x;
    if (bid < 144) {            // transpose W1 -> bf16, 12x12 tiles of 32x32
        __shared__ short tl[32][33];
        const int tx = bid % 12, ty = bid / 12;
        const int c = t & 31, r8 = t >> 5;      // 32 cols x 8 rows per pass
        #pragma unroll
        for (int rr = 0; rr < 32; rr += 8)
            tl[c][rr + r8] = f2bf(W1[(ty * 32 + rr + r8) * N_HID + tx * 32 + c]);
        __syncthreads();
        #pragma unroll
        for (int rr = 0; rr < 32; rr += 8)
            w1t[(tx * 32 + rr + r8) * N_HID + ty * 32 + c] = tl[rr + r8][c];
    } else if (bid < 288) {     // cvt W2 -> bf16 (float4/short4 per thread)
        int i = (bid - 144) * 256 + t;          // 36864 float4 groups total
        float4 v = reinterpret_cast<const float4*>(W2)[i];
        reinterpret_cast<short4*>(w2b)[i] =
            make_short4(f2bf(v.x), f2bf(v.y), f2bf(v.z), f2bf(v.w));
    } else {                    // wb1[n] = sum_k W2[n][k]*b1[k]; 2 blocks x 192
        int n = (bid - 288) * 192 + t;
        if (t < 192) {
            float s = 0.f;
            for (int k = 0; k < N_HID; k += 4) {
                float4 w = *reinterpret_cast<const float4*>(&W2[n * N_HID + k]);
                float4 b = *reinterpret_cast<const float4*>(&b1[k]);
                s += w.x * b.x + w.y * b.y + w.z * b.z + w.w * b.w;
            }
            wb1[n] = s;
        }
    }
}

// ---------- GEMM: acc[m][n] = sum_k A[m][k]*W[n][k]  (A,W bf16) ----------
// Round-0 structure (verified 96 us): A AND B staged via async global->LDS,
// double-buffered 64 KiB. Rounds 2-3 refuted both B-without-LDS variants:
// global_load_lds is fire-and-forget (no VGPR writeback on the MFMA critical
// path); register B-loads cost 96->122 us even with full VGPR budget.
// FUSED=false: out bf16 = acc + bias[n]                (tiny W12 = W2*W1)
// FUSED=true : out fp32 = acc + dd[m]*wb1[n] + d[m]*bias[n]   (final output)
template <bool FUSED>
__global__ __launch_bounds__(256) void k_gemm(const short* __restrict__ A,
                                              const short* __restrict__ W,
                                              const float* __restrict__ bias,
                                              const float* __restrict__ wb1,
                                              const float* __restrict__ dvec,
                                              const float* __restrict__ ddvec,
                                              void* __restrict__ outv,
                                              int M, int MT) {
    __shared__ short As[2][BM][BK];
    __shared__ short Bs[2][BN][BK];
    const int t = threadIdx.x;
    const int bid = blockIdx.x;
    // XCD-aware: XCD c=bid%8 gets 3 consecutive blocks sharing one m-tile
    const int m_idx = ((bid >> 3) / 3) * 8 + (bid & 7);
    const int n_idx = (bid >> 3) % 3;
    if (m_idx >= MT) return;
    const int m0 = m_idx * BM, n0 = n_idx * BN;
    const int wave = t >> 6, lane = t & 63;
    const int wm = (wave & 1) * 64, wn = (wave >> 1) * 64;
    const int l16 = lane & 15, quad = lane >> 4;
    const int srow = lane >> 3;
    const int sg8 = ((lane & 7) ^ srow) * 8;   // XOR chunk swizzle
    const int sbase = wave * 8;

    f32x4 acc[4][4] = {};

    auto stage = [&](int b, int kt) {
        #pragma unroll
        for (int p = 0; p < 4; p++) {
            int gm = m0 + p * 32 + sbase + srow;
            gm = gm < M ? gm : M - 1;
            gload_lds16(A + (size_t)gm * N_HID + kt + sg8, &As[b][p * 32 + sbase][0]);
        }
        #pragma unroll
        for (int p = 0; p < 4; p++) {
            int gn = n0 + p * 32 + sbase + srow;
            gload_lds16(W + (size_t)gn * N_HID + kt + sg8, &Bs[b][p * 32 + sbase][0]);
        }
    };

    stage(0, 0);
    #pragma unroll
    for (int kt6 = 0; kt6 < KTILES; kt6++) {
        const int b = kt6 & 1;
        __syncthreads();
        if (kt6 + 1 < KTILES) stage(1 - b, (kt6 + 1) * BK);
        #pragma unroll
        for (int kk = 0; kk < 2; kk++) {
            const int gc = kk * 4 + quad;
            bf16x8 af[4], bfr[4];
            #pragma unroll
            for (int i = 0; i < 4; i++)
                af[i] = *reinterpret_cast<const bf16x8*>(&As[b][wm + i * 16 + l16][(gc ^ (l16 & 7)) * 8]);
            #pragma unroll
            for (int j = 0; j < 4; j++)
                bfr[j] = *reinterpret_cast<const bf16x8*>(&Bs[b][wn + j * 16 + l16][(gc ^ (l16 & 7)) * 8]);
            #pragma unroll
            for (int i = 0; i < 4; i++)
                #pragma unroll
                for (int j = 0; j < 4; j++)
                    acc[i][j] = __builtin_amdgcn_mfma_f32_16x16x32_bf16(af[i], bfr[j], acc[i][j], 0, 0, 0);
        }
    }

    // C/D layout: col = lane&15, row = quad*4 + reg
    if (FUSED) {
        // fp32 direct stores: 16 lanes x 4B = full 64B lines, no RMW
        float* outf = (float*)outv;
        float dv[4][4], ddv[4][4];
        #pragma unroll
        for (int i = 0; i < 4; i++)
            #pragma unroll
            for (int r = 0; r < 4; r++) {
                int gm = m0 + wm + i * 16 + quad * 4 + r;
                int gmc = gm < M ? gm : 0;
                dv[i][r]  = dvec[gmc];
                ddv[i][r] = ddvec[gmc];
            }
        #pragma unroll
        for (int j = 0; j < 4; j++) {
            int gn = n0 + wn + j * 16 + l16;
            float wb1v = wb1[gn];
            float b2v  = bias[gn];
            #pragma unroll
            for (int i = 0; i < 4; i++) {
                int gmb = m0 + wm + i * 16 + quad * 4;
                #pragma unroll
                for (int r = 0; r < 4; r++) {
                    int gm = gmb + r;
                    if (gm < M)
                        outf[(size_t)gm * N_HID + gn] =
                            acc[i][j][r] + ddv[i][r] * wb1v + dv[i][r] * b2v;
                }
            }
        }
    } else {
        // bf16 out via LDS repack -> 16B coalesced stores
        short* outb = (short*)outv;
        __syncthreads();
        short* eps = &As[0][0][0] + wave * 4096;
        #pragma unroll
        for (int j = 0; j < 4; j++) {
            float bv = bias[n0 + wn + j * 16 + l16];
            #pragma unroll
            for (int i = 0; i < 4; i++)
                #pragma unroll
                for (int r = 0; r < 4; r++) {
                    int rw = i * 16 + quad * 4 + r;
                    int colw = j * 16 + l16;
                    int chs = ((colw >> 3) + (rw & 7) + (rw >> 3)) & 7;
                    eps[rw * 64 + chs * 8 + (colw & 7)] = f2bf(acc[i][j][r] + bv);
                }
        }
        __syncthreads();
        const int r8 = lane >> 3, ch2 = lane & 7;
        #pragma unroll
        for (int pass = 0; pass < 8; pass++) {
            int rw = pass * 8 + r8;
            int chs = (ch2 + r8 + pass) & 7;
            bf16x8 v = *reinterpret_cast<const bf16x8*>(&eps[rw * 64 + chs * 8]);
            int gm = m0 + wm + rw;
            if (gm < M)
                *reinterpret_cast<bf16x8*>(outb + (size_t)gm * N_HID + n0 + wn + ch2 * 8) = v;
        }
    }
}

// ---------- gather: one wave per destination node, edge loop unrolled x2 ----
// Wide-load layout (writer/reader/GEMM all agree; still standard row-major):
//   uint index 2*lane   : elements 4*lane, 4*lane+1   (uint2 with +1)
//   uint index 128+lane : elements 256+2*lane, +1
// 2 loads + 2 stores per row (was 3+3).
// SECOND=false: in = x (fp32), ds = sum(w)           -> d
// SECOND=true : in = g1 (bf16), ds = sum(w*din[src]) -> dd
template <bool SECOND>
__global__ __launch_bounds__(256) void k_gather(const void* __restrict__ inv,
                                                const int2* __restrict__ srcnrm,
                                                const int* __restrict__ offs,
                                                const int* __restrict__ bsum,
                                                const int* __restrict__ cur,
                                                const float* __restrict__ din,
                                                unsigned int* __restrict__ outg,
                                                float* __restrict__ dout, int N) {
    int node = (blockIdx.x * 256 + threadIdx.x) >> 6;
    if (node >= N) return;
    int lane = threadIdx.x & 63;
    int start = offs[node] + bsum[node >> 10];
    int ecnt  = cur[node];   // in-degree
    float a0 = 0.f, a1 = 0.f, a2 = 0.f, a3 = 0.f, a4 = 0.f, a5 = 0.f;
    float ds = 0.f;
    int i = 0;
    for (; i + 2 <= ecnt; i += 2) {          // pairs: independent load streams
        int2 pa = srcnrm[start + i];
        int2 pb = srcnrm[start + i + 1];
        float wa = __int_as_float(pa.y), wb = __int_as_float(pb.y);
        float va0, va1, va2, va3, va4, va5;
        float vb0, vb1, vb2, vb3, vb4, vb5;
        if (SECOND) {
            const unsigned int* ra = (const unsigned int*)inv + (size_t)pa.x * 192;
            const unsigned int* rb = (const unsigned int*)inv + (size_t)pb.x * 192;
            uint2 ua01 = *reinterpret_cast<const uint2*>(ra + 2 * lane);
            uint2 ub01 = *reinterpret_cast<const uint2*>(rb + 2 * lane);
            unsigned int ua2 = ra[128 + lane];
            unsigned int ub2 = rb[128 + lane];
            va0 = __uint_as_float(ua01.x << 16); va1 = __uint_as_float(ua01.x & 0xffff0000u);
            va2 = __uint_as_float(ua01.y << 16); va3 = __uint_as_float(ua01.y & 0xffff0000u);
            va4 = __uint_as_float(ua2 << 16);    va5 = __uint_as_float(ua2 & 0xffff0000u);
            vb0 = __uint_as_float(ub01.x << 16); vb1 = __uint_as_float(ub01.x & 0xffff0000u);
            vb2 = __uint_as_float(ub01.y << 16); vb3 = __uint_as_float(ub01.y & 0xffff0000u);
            vb4 = __uint_as_float(ub2 << 16);    vb5 = __uint_as_float(ub2 & 0xffff0000u);
            ds += wa * din[pa.x] + wb * din[pb.x];
        } else {
            const float* ra = (const float*)inv + (size_t)pa.x * 384;
            const float* rb = (const float*)inv + (size_t)pb.x * 384;
            float4 fa = *reinterpret_cast<const float4*>(ra + 4 * lane);
            float4 fb = *reinterpret_cast<const float4*>(rb + 4 * lane);
            float2 ga = *reinterpret_cast<const float2*>(ra + 256 + 2 * lane);
            float2 gb = *reinterpret_cast<const float2*>(rb + 256 + 2 * lane);
            va0 = fa.x; va1 = fa.y; va2 = fa.z; va3 = fa.w; va4 = ga.x; va5 = ga.y;
            vb0 = fb.x; vb1 = fb.y; vb2 = fb.z; vb3 = fb.w; vb4 = gb.x; vb5 = gb.y;
            ds += wa + wb;
        }
        a0 += wa * va0 + wb * vb0; a1 += wa * va1 + wb * vb1;
        a2 += wa * va2 + wb * vb2; a3 += wa * va3 + wb * vb3;
        a4 += wa * va4 + wb * vb4; a5 += wa * va5 + wb * vb5;
    }
    if (i < ecnt) {                          // tail edge
        int2 p = srcnrm[start + i];
        float w = __int_as_float(p.y);
        if (SECOND) {
            const unsigned int* r = (const unsigned int*)inv + (size_t)p.x * 192;
            uint2 u01 = *reinterpret_cast<const uint2*>(r + 2 * lane);
            unsigned int u2 = r[128 + lane];
            a0 += w * __uint_as_float(u01.x << 16);
            a1 += w * __uint_as_float(u01.x & 0xffff0000u);
            a2 += w * __uint_as_float(u01.y << 16);
            a3 += w * __uint_as_float(u01.y & 0xffff0000u);
            a4 += w * __uint_as_float(u2 << 16);
            a5 += w * __uint_as_float(u2 & 0xffff0000u);
            ds += w * din[p.x];
        } else {
            const float* r = (const float*)inv + (size_t)p.x * 384;
            float4 f = *reinterpret_cast<const float4*>(r + 4 * lane);
            float2 g = *reinterpret_cast<const float2*>(r + 256 + 2 * lane);
            a0 += w * f.x; a1 += w * f.y; a2 += w * f.z; a3 += w * f.w;
            a4 += w * g.x; a5 += w * g.y;
            ds += w;
        }
    }
    uint2 st;
    st.x = pk2(a0, a1);
    st.y = pk2(a2, a3);
    *reinterpret_cast<uint2*>(outg + (size_t)node * 192 + 2 * lane) = st;
    outg[(size_t)node * 192 + 128 + lane] = pk2(a4, a5);
    if (lane == 0) dout[node] = ds;
}

extern "C" void kernel_launch(void* const* d_in, const int* in_sizes, int n_in,
                              void* d_out, int out_size, void* d_ws, size_t ws_size,
                              hipStream_t stream) {
    const float* x  = (const float*)d_in[0];
    const int*   ei = (const int*)d_in[1];
    const float* W1 = (const float*)d_in[2];
    const float* b1 = (const float*)d_in[3];
    const float* W2 = (const float*)d_in[4];
    const float* b2 = (const float*)d_in[5];

    const int N = in_sizes[0] / N_HID;   // 100000
    const int E = in_sizes[1] / 2;       // 200000
    const int* row = ei;
    const int* col = ei + E;
    const int nb = (N + 1023) / 1024;    // 98 (<=256 for k_scan2)

    // g1 (bf16, 76.8 MB) lives in d_out's first half; dead before the final
    // GEMM rewrites all of d_out in fp32.
    unsigned int* g1 = (unsigned int*)d_out;

    auto al = [](size_t v) { return (v + 255) & ~(size_t)255; };
    char* ws = (char*)d_ws;
    size_t o = 0;
    int*   deg    = (int*)(ws + o);   o += al((size_t)N * 4);
    int*   offs   = (int*)(ws + o);   o += al((size_t)N * 4);   // cnt -> offs in place
    float* zeros  = (float*)(ws + o); o += al(N_HID * 4);       // tiny-GEMM bias
    int*   cur    = (int*)(ws + o);   o += al((size_t)N * 4);
    // --- everything above zeroed by ONE memset ---
    const size_t zlen = o;
    int*   bsum   = (int*)(ws + o);   o += al((size_t)nb * 4);
    int2*  srcnrm = (int2*)(ws + o);  o += al((size_t)E * 8);
    short* w1t    = (short*)(ws + o); o += al((size_t)N_HID * N_HID * 2);
    short* w2b    = (short*)(ws + o); o += al((size_t)N_HID * N_HID * 2);
    short* w12    = (short*)(ws + o); o += al((size_t)N_HID * N_HID * 2);
    float* wb1    = (float*)(ws + o); o += al(N_HID * 4);
    float* dvec   = (float*)(ws + o); o += al((size_t)N * 4);
    float* ddvec  = (float*)(ws + o); o += al((size_t)N * 4);
    unsigned int* g2 = (unsigned int*)(ws + o);                  // N*384 bf16

    hipMemsetAsync(deg, 0, zlen, stream);

    // CSR build: deg/cnt histograms -> scan -> slot fill (norm from deg).
    // bsum is applied inside k_fill / k_gather (k_scan3 eliminated).
    k_hist<<<(E + 255) / 256, 256, 0, stream>>>(row, col, deg, offs, E);
    k_scan1<<<nb, 256, 0, stream>>>(offs, offs, bsum, N);
    k_scan2<<<1, 256, 0, stream>>>(bsum, nb);
    k_fill<<<(E + 255) / 256, 256, 0, stream>>>(row, col, deg, offs, bsum, cur, srcnrm, E);

    // W-prep + tiny GEMM: w12 = W2 @ W1 (bf16), wb1 = W2 @ b1
    k_prep<<<290, 256, 0, stream>>>(W1, W2, b1, w1t, w2b, wb1);
    k_gemm<false><<<24, 256, 0, stream>>>(w2b, w1t, zeros, nullptr, nullptr, nullptr,
                                          w12, N_HID, 3);

    // g1 = A_hat @ x (fp32 in, bf16 out), d = A_hat @ 1
    // g2 = A_hat @ g1,                    dd = A_hat @ d
    const int gat_blocks = (int)(((size_t)N * 64 + 255) / 256);
    k_gather<false><<<gat_blocks, 256, 0, stream>>>(x,  srcnrm, offs, bsum, cur, nullptr, g1, dvec, N);
    k_gather<true><<<gat_blocks, 256, 0, stream>>>(g1, srcnrm, offs, bsum, cur, dvec, g2, ddvec, N);

    // out = g2 @ w12^T + dd*wb1^T + d*b2^T   (fp32, fully rewrites d_out)
    const int MT = (N + BM - 1) / BM;            // 782
    const int gblocks = ((MT + 7) / 8) * 24;     // 2352
    k_gemm<true><<<gblocks, 256, 0, stream>>>((const short*)g2, w12, b2, wb1, dvec, ddvec,
                                              d_out, N, MT);
}

// Round 5
// 464.927 us; speedup vs baseline: 1.1241x; 1.0003x over previous
//
#include <hip/hip_runtime.h>
#include <hip/hip_bf16.h>
#include <cstdint>

#define N_HID 384
#define BM 64
#define BN 128
#define BK 64
#define KTILES 6   // N_HID / BK

typedef __attribute__((ext_vector_type(8))) short bf16x8;
typedef __attribute__((ext_vector_type(4))) float f32x4;

static __device__ __forceinline__ short f2bf(float f) {
    union { __hip_bfloat16 h; short s; } u;
    u.h = __float2bfloat16(f);  // RNE
    return u.s;
}

static __device__ __forceinline__ unsigned int pk2(float lo, float hi) {
    return (unsigned int)(unsigned short)f2bf(lo) |
           ((unsigned int)(unsigned short)f2bf(hi) << 16);
}

// async global->LDS, 16B per lane; LDS dest = wave-uniform base + lane*16
static __device__ __forceinline__ void gload_lds16(const void* g, void* l) {
    __builtin_amdgcn_global_load_lds(
        (const __attribute__((address_space(1))) void*)g,
        (__attribute__((address_space(3))) void*)l,
        16, 0, 0);
}

// merged edge histograms: deg over row (for norm), cnt over col (for CSR)
__global__ __launch_bounds__(256) void k_hist(const int* __restrict__ row,
                                              const int* __restrict__ col,
                                              int* __restrict__ deg,
                                              int* __restrict__ cnt, int E) {
    int i = blockIdx.x * 256 + threadIdx.x;
    if (i < E) {
        atomicAdd(&deg[row[i]], 1);
        atomicAdd(&cnt[col[i]], 1);
    }
}

// ---------- CSR-by-destination build ----------

__global__ __launch_bounds__(256) void k_scan1(const int* __restrict__ cnt,
                                               int* __restrict__ offs,
                                               int* __restrict__ bsum, int N) {
    __shared__ int s[256];
    const int t = threadIdx.x;
    const int base = blockIdx.x * 1024 + t * 4;
    int v[4], tot = 0;
    #pragma unroll
    for (int i = 0; i < 4; i++) { v[i] = (base + i < N) ? cnt[base + i] : 0; tot += v[i]; }
    s[t] = tot;
    __syncthreads();
    #pragma unroll
    for (int off = 1; off < 256; off <<= 1) {
        int x = (t >= off) ? s[t - off] : 0;
        __syncthreads();
        s[t] += x;
        __syncthreads();
    }
    if (t == 255) bsum[blockIdx.x] = s[255];
    int run = s[t] - tot;
    #pragma unroll
    for (int i = 0; i < 4; i++) { if (base + i < N) offs[base + i] = run; run += v[i]; }
}

__global__ __launch_bounds__(256) void k_scan2(int* __restrict__ bsum, int nb) {
    __shared__ int s[256];
    const int t = threadIdx.x;
    int v = (t < nb) ? bsum[t] : 0;
    s[t] = v;
    __syncthreads();
    #pragma unroll
    for (int off = 1; off < 256; off <<= 1) {
        int x = (t >= off) ? s[t - off] : 0;
        __syncthreads();
        s[t] += x;
        __syncthreads();
    }
    if (t < nb) bsum[t] = s[t] - v;   // exclusive
}

// slot fill: packed (src, norm) per CSR slot; norm computed from deg directly.
// bsum folded in here (k_scan3 eliminated): global offset = offs[c]+bsum[c>>10]
__global__ __launch_bounds__(256) void k_fill(const int* __restrict__ row,
                                              const int* __restrict__ col,
                                              const int* __restrict__ deg,
                                              const int* __restrict__ offs,
                                              const int* __restrict__ bsum,
                                              int* __restrict__ cur,
                                              int2* __restrict__ srcnrm, int E) {
    int e = blockIdx.x * 256 + threadIdx.x;
    if (e >= E) return;
    int r = row[e], c = col[e];
    int slot = offs[c] + bsum[c >> 10] + atomicAdd(&cur[c], 1);
    int2 p;
    p.x = r;
    p.y = __float_as_int(rsqrtf((float)deg[r]) * rsqrtf((float)deg[c]));
    srcnrm[slot] = p;
}

// ---------- W-prep: w1t = W1^T (bf16), w2b = W2 (bf16), wb1 = W2 @ b1 (fp32)
__global__ __launch_bounds__(256) void k_prep(const float* __restrict__ W1,
                                              const float* __restrict__ W2,
                                              const float* __restrict__ b1,
                                              short* __restrict__ w1t,
                                              short* __restrict__ w2b,
                                              float* __restrict__ wb1) {
    const int bid = blockIdx.x, t = threadIdx.x;
    if (bid < 144) {            // transpose W1 -> bf16, 12x12 tiles of 32x32
        __shared__ short tl[32][33];
        const int tx = bid % 12, ty = bid / 12;
        const int c = t & 31, r8 = t >> 5;      // 32 cols x 8 rows per pass
        #pragma unroll
        for (int rr = 0; rr < 32; rr += 8)
            tl[c][rr + r8] = f2bf(W1[(ty * 32 + rr + r8) * N_HID + tx * 32 + c]);
        __syncthreads();
        #pragma unroll
        for (int rr = 0; rr < 32; rr += 8)
            w1t[(tx * 32 + rr + r8) * N_HID + ty * 32 + c] = tl[rr + r8][c];
    } else if (bid < 288) {     // cvt W2 -> bf16 (float4/short4 per thread)
        int i = (bid - 144) * 256 + t;          // 36864 float4 groups total
        float4 v = reinterpret_cast<const float4*>(W2)[i];
        reinterpret_cast<short4*>(w2b)[i] =
            make_short4(f2bf(v.x), f2bf(v.y), f2bf(v.z), f2bf(v.w));
    } else {                    // wb1[n] = sum_k W2[n][k]*b1[k]; 2 blocks x 192
        int n = (bid - 288) * 192 + t;
        if (t < 192) {
            float s = 0.f;
            for (int k = 0; k < N_HID; k += 4) {
                float4 w = *reinterpret_cast<const float4*>(&W2[n * N_HID + k]);
                float4 b = *reinterpret_cast<const float4*>(&b1[k]);
                s += w.x * b.x + w.y * b.y + w.z * b.z + w.w * b.w;
            }
            wb1[n] = s;
        }
    }
}

// ---------- GEMM: acc[m][n] = sum_k A[m][k]*W[n][k]  (A,W bf16) ----------
// BM=64 re-tile of the verified round-0 structure: A+B staged via async
// global->LDS double-buffered, but LDS = 48 KiB -> 3 blocks/CU (12 waves/CU,
// +50% TLP vs 128-tile's 2 blocks) at ZERO extra HBM traffic (A reuse is set
// by the 3 n-tiles, unchanged). 4 waves each own 64x32 of C (wn=wave*32),
// acc[4][2] = 32 AGPR; launch_bounds(256,3) caps 170 regs/wave (generous --
// round-2's 128-cap pathology avoided).
// Rounds 2-3 refuted B-without-LDS (fire-and-forget gload_lds beats register
// B-loads on the MFMA critical path).
// FUSED=false: out bf16 = acc + bias[n]                (tiny W12 = W2*W1)
// FUSED=true : out fp32 = acc + dd[m]*wb1[n] + d[m]*bias[n]   (final output)
template <bool FUSED>
__global__ __launch_bounds__(256, 3) void k_gemm(const short* __restrict__ A,
                                                 const short* __restrict__ W,
                                                 const float* __restrict__ bias,
                                                 const float* __restrict__ wb1,
                                                 const float* __restrict__ dvec,
                                                 const float* __restrict__ ddvec,
                                                 void* __restrict__ outv,
                                                 int M, int MT) {
    __shared__ short As[2][BM][BK];   // 16 KiB
    __shared__ short Bs[2][BN][BK];   // 32 KiB
    const int t = threadIdx.x;
    const int bid = blockIdx.x;
    // XCD-aware: XCD c=bid%8 gets 3 consecutive blocks sharing one m-tile
    const int m_idx = ((bid >> 3) / 3) * 8 + (bid & 7);
    const int n_idx = (bid >> 3) % 3;
    if (m_idx >= MT) return;
    const int m0 = m_idx * BM, n0 = n_idx * BN;
    const int wave = t >> 6, lane = t & 63;
    const int wn = wave * 32;              // each wave: all 64 rows x 32 cols
    const int l16 = lane & 15, quad = lane >> 4;
    const int srow = lane >> 3;
    const int sg8 = ((lane & 7) ^ srow) * 8;   // XOR chunk swizzle
    const int sbase = wave * 8;

    f32x4 acc[4][2] = {};

    auto stage = [&](int b, int kt) {
        #pragma unroll
        for (int p = 0; p < 2; p++) {          // A: 64 rows
            int gm = m0 + p * 32 + sbase + srow;
            gm = gm < M ? gm : M - 1;
            gload_lds16(A + (size_t)gm * N_HID + kt + sg8, &As[b][p * 32 + sbase][0]);
        }
        #pragma unroll
        for (int p = 0; p < 4; p++) {          // B: 128 rows
            int gn = n0 + p * 32 + sbase + srow;
            gload_lds16(W + (size_t)gn * N_HID + kt + sg8, &Bs[b][p * 32 + sbase][0]);
        }
    };

    stage(0, 0);
    #pragma unroll
    for (int kt6 = 0; kt6 < KTILES; kt6++) {
        const int b = kt6 & 1;
        __syncthreads();
        if (kt6 + 1 < KTILES) stage(1 - b, (kt6 + 1) * BK);
        #pragma unroll
        for (int kk = 0; kk < 2; kk++) {
            const int gc = kk * 4 + quad;
            bf16x8 af[4], bfr[2];
            #pragma unroll
            for (int i = 0; i < 4; i++)
                af[i] = *reinterpret_cast<const bf16x8*>(&As[b][i * 16 + l16][(gc ^ (l16 & 7)) * 8]);
            #pragma unroll
            for (int j = 0; j < 2; j++)
                bfr[j] = *reinterpret_cast<const bf16x8*>(&Bs[b][wn + j * 16 + l16][(gc ^ (l16 & 7)) * 8]);
            #pragma unroll
            for (int i = 0; i < 4; i++)
                #pragma unroll
                for (int j = 0; j < 2; j++)
                    acc[i][j] = __builtin_amdgcn_mfma_f32_16x16x32_bf16(af[i], bfr[j], acc[i][j], 0, 0, 0);
        }
    }

    // C/D layout: col = lane&15, row = quad*4 + reg
    if (FUSED) {
        // fp32 direct stores: 16 lanes x 4B = full 64B lines, no RMW
        float* outf = (float*)outv;
        float dv[4][4], ddv[4][4];
        #pragma unroll
        for (int i = 0; i < 4; i++)
            #pragma unroll
            for (int r = 0; r < 4; r++) {
                int gm = m0 + i * 16 + quad * 4 + r;
                int gmc = gm < M ? gm : 0;
                dv[i][r]  = dvec[gmc];
                ddv[i][r] = ddvec[gmc];
            }
        #pragma unroll
        for (int j = 0; j < 2; j++) {
            int gn = n0 + wn + j * 16 + l16;
            float wb1v = wb1[gn];
            float b2v  = bias[gn];
            #pragma unroll
            for (int i = 0; i < 4; i++) {
                int gmb = m0 + i * 16 + quad * 4;
                #pragma unroll
                for (int r = 0; r < 4; r++) {
                    int gm = gmb + r;
                    if (gm < M)
                        outf[(size_t)gm * N_HID + gn] =
                            acc[i][j][r] + ddv[i][r] * wb1v + dv[i][r] * b2v;
                }
            }
        }
    } else {
        // bf16 out via LDS repack -> 16B coalesced stores
        short* outb = (short*)outv;
        __syncthreads();
        short* eps = &As[0][0][0] + wave * 2048;   // 4 waves x 4KB = all of As
        #pragma unroll
        for (int j = 0; j < 2; j++) {
            float bv = bias[n0 + wn + j * 16 + l16];
            #pragma unroll
            for (int i = 0; i < 4; i++)
                #pragma unroll
                for (int r = 0; r < 4; r++) {
                    int rw = i * 16 + quad * 4 + r;      // 0..63
                    int colw = j * 16 + l16;             // 0..31
                    int chs = ((colw >> 3) + rw) & 3;    // chunk swizzle
                    eps[rw * 32 + chs * 8 + (colw & 7)] = f2bf(acc[i][j][r] + bv);
                }
        }
        __syncthreads();
        #pragma unroll
        for (int pass = 0; pass < 4; pass++) {
            int rw = pass * 16 + (lane >> 2);
            int cc = lane & 3;
            int chs = (cc + rw) & 3;                     // inverse of write swz
            bf16x8 v = *reinterpret_cast<const bf16x8*>(&eps[rw * 32 + chs * 8]);
            int gm = m0 + rw;
            if (gm < M)
                *reinterpret_cast<bf16x8*>(outb + (size_t)gm * N_HID + n0 + wn + cc * 8) = v;
        }
    }
}

// ---------- gather: one wave per destination node, edge loop unrolled x2 ----
// Wide-load layout (writer/reader/GEMM all agree; still standard row-major):
//   uint index 2*lane   : elements 4*lane, 4*lane+1   (uint2 with +1)
//   uint index 128+lane : elements 256+2*lane, +1
// 2 loads + 2 stores per row (was 3+3).
// SECOND=false: in = x (fp32), ds = sum(w)           -> d
// SECOND=true : in = g1 (bf16), ds = sum(w*din[src]) -> dd
template <bool SECOND>
__global__ __launch_bounds__(256) void k_gather(const void* __restrict__ inv,
                                                const int2* __restrict__ srcnrm,
                                                const int* __restrict__ offs,
                                                const int* __restrict__ bsum,
                                                const int* __restrict__ cur,
                                                const float* __restrict__ din,
                                                unsigned int* __restrict__ outg,
                                                float* __restrict__ dout, int N) {
    int node = (blockIdx.x * 256 + threadIdx.x) >> 6;
    if (node >= N) return;
    int lane = threadIdx.x & 63;
    int start = offs[node] + bsum[node >> 10];
    int ecnt  = cur[node];   // in-degree
    float a0 = 0.f, a1 = 0.f, a2 = 0.f, a3 = 0.f, a4 = 0.f, a5 = 0.f;
    float ds = 0.f;
    int i = 0;
    for (; i + 2 <= ecnt; i += 2) {          // pairs: independent load streams
        int2 pa = srcnrm[start + i];
        int2 pb = srcnrm[start + i + 1];
        float wa = __int_as_float(pa.y), wb = __int_as_float(pb.y);
        float va0, va1, va2, va3, va4, va5;
        float vb0, vb1, vb2, vb3, vb4, vb5;
        if (SECOND) {
            const unsigned int* ra = (const unsigned int*)inv + (size_t)pa.x * 192;
            const unsigned int* rb = (const unsigned int*)inv + (size_t)pb.x * 192;
            uint2 ua01 = *reinterpret_cast<const uint2*>(ra + 2 * lane);
            uint2 ub01 = *reinterpret_cast<const uint2*>(rb + 2 * lane);
            unsigned int ua2 = ra[128 + lane];
            unsigned int ub2 = rb[128 + lane];
            va0 = __uint_as_float(ua01.x << 16); va1 = __uint_as_float(ua01.x & 0xffff0000u);
            va2 = __uint_as_float(ua01.y << 16); va3 = __uint_as_float(ua01.y & 0xffff0000u);
            va4 = __uint_as_float(ua2 << 16);    va5 = __uint_as_float(ua2 & 0xffff0000u);
            vb0 = __uint_as_float(ub01.x << 16); vb1 = __uint_as_float(ub01.x & 0xffff0000u);
            vb2 = __uint_as_float(ub01.y << 16); vb3 = __uint_as_float(ub01.y & 0xffff0000u);
            vb4 = __uint_as_float(ub2 << 16);    vb5 = __uint_as_float(ub2 & 0xffff0000u);
            ds += wa * din[pa.x] + wb * din[pb.x];
        } else {
            const float* ra = (const float*)inv + (size_t)pa.x * 384;
            const float* rb = (const float*)inv + (size_t)pb.x * 384;
            float4 fa = *reinterpret_cast<const float4*>(ra + 4 * lane);
            float4 fb = *reinterpret_cast<const float4*>(rb + 4 * lane);
            float2 ga = *reinterpret_cast<const float2*>(ra + 256 + 2 * lane);
            float2 gb = *reinterpret_cast<const float2*>(rb + 256 + 2 * lane);
            va0 = fa.x; va1 = fa.y; va2 = fa.z; va3 = fa.w; va4 = ga.x; va5 = ga.y;
            vb0 = fb.x; vb1 = fb.y; vb2 = fb.z; vb3 = fb.w; vb4 = gb.x; vb5 = gb.y;
            ds += wa + wb;
        }
        a0 += wa * va0 + wb * vb0; a1 += wa * va1 + wb * vb1;
        a2 += wa * va2 + wb * vb2; a3 += wa * va3 + wb * vb3;
        a4 += wa * va4 + wb * vb4; a5 += wa * va5 + wb * vb5;
    }
    if (i < ecnt) {                          // tail edge
        int2 p = srcnrm[start + i];
        float w = __int_as_float(p.y);
        if (SECOND) {
            const unsigned int* r = (const unsigned int*)inv + (size_t)p.x * 192;
            uint2 u01 = *reinterpret_cast<const uint2*>(r + 2 * lane);
            unsigned int u2 = r[128 + lane];
            a0 += w * __uint_as_float(u01.x << 16);
            a1 += w * __uint_as_float(u01.x & 0xffff0000u);
            a2 += w * __uint_as_float(u01.y << 16);
            a3 += w * __uint_as_float(u01.y & 0xffff0000u);
            a4 += w * __uint_as_float(u2 << 16);
            a5 += w * __uint_as_float(u2 & 0xffff0000u);
            ds += w * din[p.x];
        } else {
            const float* r = (const float*)inv + (size_t)p.x * 384;
            float4 f = *reinterpret_cast<const float4*>(r + 4 * lane);
            float2 g = *reinterpret_cast<const float2*>(r + 256 + 2 * lane);
            a0 += w * f.x; a1 += w * f.y; a2 += w * f.z; a3 += w * f.w;
            a4 += w * g.x; a5 += w * g.y;
            ds += w;
        }
    }
    uint2 st;
    st.x = pk2(a0, a1);
    st.y = pk2(a2, a3);
    *reinterpret_cast<uint2*>(outg + (size_t)node * 192 + 2 * lane) = st;
    outg[(size_t)node * 192 + 128 + lane] = pk2(a4, a5);
    if (lane == 0) dout[node] = ds;
}

extern "C" void kernel_launch(void* const* d_in, const int* in_sizes, int n_in,
                              void* d_out, int out_size, void* d_ws, size_t ws_size,
                              hipStream_t stream) {
    const float* x  = (const float*)d_in[0];
    const int*   ei = (const int*)d_in[1];
    const float* W1 = (const float*)d_in[2];
    const float* b1 = (const float*)d_in[3];
    const float* W2 = (const float*)d_in[4];
    const float* b2 = (const float*)d_in[5];

    const int N = in_sizes[0] / N_HID;   // 100000
    const int E = in_sizes[1] / 2;       // 200000
    const int* row = ei;
    const int* col = ei + E;
    const int nb = (N + 1023) / 1024;    // 98 (<=256 for k_scan2)

    // g1 (bf16, 76.8 MB) lives in d_out's first half; dead before the final
    // GEMM rewrites all of d_out in fp32.
    unsigned int* g1 = (unsigned int*)d_out;

    auto al = [](size_t v) { return (v + 255) & ~(size_t)255; };
    char* ws = (char*)d_ws;
    size_t o = 0;
    int*   deg    = (int*)(ws + o);   o += al((size_t)N * 4);
    int*   offs   = (int*)(ws + o);   o += al((size_t)N * 4);   // cnt -> offs in place
    float* zeros  = (float*)(ws + o); o += al(N_HID * 4);       // tiny-GEMM bias
    int*   cur    = (int*)(ws + o);   o += al((size_t)N * 4);
    // --- everything above zeroed by ONE memset ---
    const size_t zlen = o;
    int*   bsum   = (int*)(ws + o);   o += al((size_t)nb * 4);
    int2*  srcnrm = (int2*)(ws + o);  o += al((size_t)E * 8);
    short* w1t    = (short*)(ws + o); o += al((size_t)N_HID * N_HID * 2);
    short* w2b    = (short*)(ws + o); o += al((size_t)N_HID * N_HID * 2);
    short* w12    = (short*)(ws + o); o += al((size_t)N_HID * N_HID * 2);
    float* wb1    = (float*)(ws + o); o += al(N_HID * 4);
    float* dvec   = (float*)(ws + o); o += al((size_t)N * 4);
    float* ddvec  = (float*)(ws + o); o += al((size_t)N * 4);
    unsigned int* g2 = (unsigned int*)(ws + o);                  // N*384 bf16

    hipMemsetAsync(deg, 0, zlen, stream);

    // CSR build: deg/cnt histograms -> scan -> slot fill (norm from deg).
    // bsum is applied inside k_fill / k_gather (k_scan3 eliminated).
    k_hist<<<(E + 255) / 256, 256, 0, stream>>>(row, col, deg, offs, E);
    k_scan1<<<nb, 256, 0, stream>>>(offs, offs, bsum, N);
    k_scan2<<<1, 256, 0, stream>>>(bsum, nb);
    k_fill<<<(E + 255) / 256, 256, 0, stream>>>(row, col, deg, offs, bsum, cur, srcnrm, E);

    // W-prep + tiny GEMM: w12 = W2 @ W1 (bf16), wb1 = W2 @ b1
    k_prep<<<290, 256, 0, stream>>>(W1, W2, b1, w1t, w2b, wb1);
    k_gemm<false><<<24, 256, 0, stream>>>(w2b, w1t, zeros, nullptr, nullptr, nullptr,
                                          w12, N_HID, N_HID / BM);

    // g1 = A_hat @ x (fp32 in, bf16 out), d = A_hat @ 1
    // g2 = A_hat @ g1,                    dd = A_hat @ d
    const int gat_blocks = (int)(((size_t)N * 64 + 255) / 256);
    k_gather<false><<<gat_blocks, 256, 0, stream>>>(x,  srcnrm, offs, bsum, cur, nullptr, g1, dvec, N);
    k_gather<true><<<gat_blocks, 256, 0, stream>>>(g1, srcnrm, offs, bsum, cur, dvec, g2, ddvec, N);

    // out = g2 @ w12^T + dd*wb1^T + d*b2^T   (fp32, fully rewrites d_out)
    const int MT = (N + BM - 1) / BM;            // 1563
    const int gblocks = ((MT + 7) / 8) * 24;     // 4704
    k_gemm<true><<<gblocks, 256, 0, stream>>>((const short*)g2, w12, b2, wb1, dvec, ddvec,
                                              d_out, N, MT);
}